// Round 5
// baseline (372.167 us; speedup 1.0000x reference)
//
#include <hip/hip_runtime.h>
#include <stdint.h>

#define N_NODES 100000
#define N_EDGES 1600000
#define IN_DIM 32
#define OUT_DIM 64
#define N_REL 8
#define NSEG (N_NODES * N_REL)     // 800000
#define EPS 1e-10f
#define N_KK 9                      // K-tiles of 32 (8 rel + 1 self)
#define SWG_ELEMS (N_KK * 4 * 64 * 8)  // 18432 bf16 in b-frag order

// counting-sort scan geometry
#define SCAN_ELEMS 4096                         // elements per scan block (256 thr x 16)
#define SCAN_NB ((NSEG + SCAN_ELEMS - 1) / SCAN_ELEMS)  // 196 (<=256: in-block reduce ok)

// two-phase partition geometry
#define NB 32                                   // dst-range buckets
#define NODES_PER_BUCKET 3125                   // 100000 / 32
#define SEGS_PER_BUCKET (NODES_PER_BUCKET * N_REL)  // 25000
#define P1_EDGES 4096                           // edges per part1 block (16/thread)
#define P1_BLOCKS ((N_EDGES + P1_EDGES - 1) / P1_EDGES) // 391
#define P2_SUB 16                               // sub-chunks per bucket (512 blocks)

// merged setup kernel block ranges
#define HIST_BLOCKS ((N_EDGES + 255) / 256)               // 6250
#define XBF_BLOCKS  ((N_NODES * IN_DIM / 8 + 255) / 256)  // 1563
#define PREP_BLOCKS ((SWG_ELEMS + OUT_DIM + 255) / 256)   // 73

typedef __attribute__((ext_vector_type(8))) short bf16x8;
typedef __attribute__((ext_vector_type(4))) float f32x4;

static __device__ __forceinline__ float bflo(uint32_t u) { return __uint_as_float(u << 16); }
static __device__ __forceinline__ float bfhi(uint32_t u) { return __uint_as_float(u & 0xffff0000u); }
static __device__ __forceinline__ uint16_t f2bf(float f) {
    uint32_t u = __float_as_uint(f);
    return (uint16_t)((u + 0x7fffu + ((u >> 16) & 1u)) >> 16); // RNE
}

// ---------------------------------------------------------------------------
// Dtype probe (earlier rounds proved fp32; kept for robustness, ~3us).
// ---------------------------------------------------------------------------
__global__ __launch_bounds__(256) void detect_kernel(const uint32_t* __restrict__ xw,
                                                     int* __restrict__ flag) {
    __shared__ int cnt;
    if (threadIdx.x == 0) cnt = 0;
    __syncthreads();
    int c = 0;
    for (int k = threadIdx.x; k < 4096; k += 256) {
        uint32_t w = xw[k];
        uint32_t e = (w >> 7) & 0xffu;
        c += (e >= 160u) ? 1 : 0;
    }
    atomicAdd(&cnt, c);
    __syncthreads();
    if (threadIdx.x == 0) *flag = (cnt > 64) ? 1 : 0;  // 1 = fp32 inputs
}

// ---------------------------------------------------------------------------
// setup: merged hist + xbf + prep (block-range dispatch; saves 2 launches).
//   blocks [0, HIST_BLOCKS):                segment-count histogram
//   blocks [HIST_BLOCKS, +XBF_BLOCKS):      x -> bf16 copy
//   blocks [.., +PREP_BLOCKS):              W swizzle + bias fuse
// ---------------------------------------------------------------------------
__global__ __launch_bounds__(256) void setup_kernel(
    const int* __restrict__ el,
    const void* __restrict__ x,
    const void* __restrict__ Wl, const void* __restrict__ Ws,
    const void* __restrict__ bl, const void* __restrict__ bs,
    const int* __restrict__ flag,
    uint32_t* __restrict__ cnt,       // = cursor region (zeroed)
    uint16_t* __restrict__ xbf,
    uint16_t* __restrict__ sWg,
    float* __restrict__ biasv)
{
    int bid = blockIdx.x;
    if (bid < HIST_BLOCKS) {
        int e = bid * 256 + threadIdx.x;
        if (e >= N_EDGES) return;
        int dst = el[e * 3 + 1];
        int rel = el[e * 3 + 2];
        atomicAdd(&cnt[dst * N_REL + rel], 1u);
        return;
    }
    bid -= HIST_BLOCKS;
    if (bid < XBF_BLOCKS) {
        int i = bid * 256 + threadIdx.x;           // one thread = 8 elements
        if (i >= N_NODES * IN_DIM / 8) return;
        if (*flag) {
            const float4 v0 = ((const float4*)x)[(size_t)i * 2];
            const float4 v1 = ((const float4*)x)[(size_t)i * 2 + 1];
            bf16x8 r;
            r[0] = (short)f2bf(v0.x); r[1] = (short)f2bf(v0.y);
            r[2] = (short)f2bf(v0.z); r[3] = (short)f2bf(v0.w);
            r[4] = (short)f2bf(v1.x); r[5] = (short)f2bf(v1.y);
            r[6] = (short)f2bf(v1.z); r[7] = (short)f2bf(v1.w);
            *(bf16x8*)(xbf + (size_t)i * 8) = r;
        } else {
            *(bf16x8*)(xbf + (size_t)i * 8) = ((const bf16x8*)x)[i];
        }
        return;
    }
    bid -= XBF_BLOCKS;
    {
        int f32 = *flag;
        int idx = bid * 256 + threadIdx.x;
        if (idx < SWG_ELEMS) {
            int j    = idx & 7;
            int lane = (idx >> 3) & 63;
            int ot   = (idx >> 9) & 3;
            int kk   = idx >> 11;
            int quad = lane >> 4;
            int k = kk * 32 + quad * 8 + j;
            int o = ot * 16 + (lane & 15);
            if (f32) {
                float v = (k < 256) ? ((const float*)Wl)[(size_t)k * OUT_DIM + o]
                                    : ((const float*)Ws)[(size_t)(k - 256) * OUT_DIM + o];
                sWg[idx] = f2bf(v);
            } else {
                sWg[idx] = (k < 256) ? ((const uint16_t*)Wl)[(size_t)k * OUT_DIM + o]
                                     : ((const uint16_t*)Ws)[(size_t)(k - 256) * OUT_DIM + o];
            }
        } else if (idx < SWG_ELEMS + OUT_DIM) {
            int o = idx - SWG_ELEMS;
            if (f32) biasv[o] = ((const float*)bl)[o] + ((const float*)bs)[o];
            else     biasv[o] = bflo((uint32_t)((const uint16_t*)bl)[o])
                              + bflo((uint32_t)((const uint16_t*)bs)[o]);
        }
    }
}

// ---------------------------------------------------------------------------
// scan1: per-block sums of counts (SCAN_ELEMS per block) -> bsum[196].
// ---------------------------------------------------------------------------
__global__ __launch_bounds__(256) void scan1_kernel(const uint32_t* __restrict__ cnt,
                                                    uint32_t* __restrict__ bsum) {
    int base = blockIdx.x * SCAN_ELEMS + threadIdx.x * 16;
    uint32_t s = 0;
    #pragma unroll
    for (int j = 0; j < 16; ++j) {
        int i = base + j;
        s += (i < NSEG) ? cnt[i] : 0u;
    }
    __shared__ uint32_t ls[256];
    ls[threadIdx.x] = s;
    __syncthreads();
    #pragma unroll
    for (int off = 128; off > 0; off >>= 1) {
        if (threadIdx.x < off) ls[threadIdx.x] += ls[threadIdx.x + off];
        __syncthreads();
    }
    if (threadIdx.x == 0) bsum[blockIdx.x] = ls[0];
}

// ---------------------------------------------------------------------------
// scan3 (scan2 folded in): each block reduces bsum[0..blockIdx) in-block
// (SCAN_NB=196 <= 256 threads), then in-block exclusive scan of counts ->
// ptr & cursor.
// ---------------------------------------------------------------------------
__global__ __launch_bounds__(256) void scan3_kernel(const uint32_t* __restrict__ bsum,
                                                    uint32_t* __restrict__ ptr,
                                                    uint32_t* __restrict__ cursor) {
    int tid = threadIdx.x;
    __shared__ uint32_t ls[256];

    // boff = sum of bsum[i] for i < blockIdx.x  (replaces scan2)
    ls[tid] = (tid < (int)blockIdx.x) ? bsum[tid] : 0u;
    __syncthreads();
    #pragma unroll
    for (int off = 128; off > 0; off >>= 1) {
        if (tid < off) ls[tid] += ls[tid + off];
        __syncthreads();
    }
    uint32_t boff = ls[0];
    __syncthreads();

    int base = blockIdx.x * SCAN_ELEMS + tid * 16;
    uint32_t v[16];
    uint32_t run = 0;
    #pragma unroll
    for (int j = 0; j < 16; ++j) {
        int i = base + j;
        uint32_t c = (i < NSEG) ? cursor[i] : 0u;  // cursor currently holds counts
        v[j] = run;
        run += c;
    }
    ls[tid] = run;
    __syncthreads();
    // Hillis-Steele inclusive scan over 256 thread totals
    for (int off = 1; off < 256; off <<= 1) {
        uint32_t t = (tid >= off) ? ls[tid - off] : 0u;
        __syncthreads();
        ls[tid] += t;
        __syncthreads();
    }
    uint32_t texcl = ls[tid] - run;
    #pragma unroll
    for (int j = 0; j < 16; ++j) {
        int i = base + j;
        if (i < NSEG) {
            uint32_t val = boff + texcl + v[j];
            ptr[i]    = val;
            cursor[i] = val;   // running cursor for part2
        }
    }
    if (blockIdx.x == 0 && tid == 0) ptr[NSEG] = N_EDGES;
}

// ---------------------------------------------------------------------------
// part1: bucket-partition the edges (32 dst-range buckets, 3125 nodes each).
// Each block: 4096 edges -> LDS histogram -> ONE global atomic per bucket
// reserves a contiguous window -> ~1KB contiguous record batches per bucket.
// Record: uint2{ src | dstlow<<17 | rel<<29 , w_bits } (17+12+3 = 32 bits).
// Replaces the round-3/4 sort's 222MB of amplified traffic with ~40MB.
// ---------------------------------------------------------------------------
__global__ __launch_bounds__(256) void part1_kernel(const int* __restrict__ el,
                                                    const void* __restrict__ ew,
                                                    const int* __restrict__ flag,
                                                    const uint32_t* __restrict__ ptr,
                                                    uint32_t* __restrict__ gcursor,
                                                    uint2* __restrict__ part) {
    __shared__ uint32_t cnt[NB], base[NB];
    int tid = threadIdx.x;
    if (tid < NB) cnt[tid] = 0;
    __syncthreads();
    int f32 = *flag;
    int e0 = blockIdx.x * P1_EDGES;

    uint32_t meta[16], wbits[16], bk[16], my[16];
    #pragma unroll
    for (int j = 0; j < 16; ++j) {
        int e = e0 + j * 256 + tid;
        if (e < N_EDGES) {
            int src = el[e * 3 + 0];
            int dst = el[e * 3 + 1];
            int rel = el[e * 3 + 2];
            int b  = dst / NODES_PER_BUCKET;           // 0..31 (magic-mul)
            int dl = dst - b * NODES_PER_BUCKET;       // < 3125 (12 bits)
            meta[j]  = (uint32_t)src | ((uint32_t)dl << 17) | ((uint32_t)rel << 29);
            wbits[j] = f32 ? ((const uint32_t*)ew)[e]
                           : ((uint32_t)((const uint16_t*)ew)[e] << 16);
            bk[j] = (uint32_t)b;
            my[j] = atomicAdd(&cnt[b], 1u);
        } else {
            bk[j] = 0xffffffffu;
        }
    }
    __syncthreads();
    if (tid < NB) {
        uint32_t c = cnt[tid];
        base[tid] = c ? (ptr[(size_t)tid * SEGS_PER_BUCKET] + atomicAdd(&gcursor[tid], c)) : 0u;
    }
    __syncthreads();
    #pragma unroll
    for (int j = 0; j < 16; ++j) {
        if (bk[j] != 0xffffffffu)
            part[(size_t)base[bk[j]] + my[j]] = make_uint2(meta[j], wbits[j]);
    }
}

// ---------------------------------------------------------------------------
// part2: per-segment scatter within each bucket. blockIdx = s*32 + b, so
// blockIdx%8 = b%8 -> ALL 16 sub-chunks of bucket b land on XCD b%8
// (round-robin dispatch, measured m09). Bucket cursor (100KB) + output
// window (~400KB) stay L2-resident on that XCD (4 buckets x 0.5MB < 4MB)
// -> full-line writebacks, ~1x write amp.
// ---------------------------------------------------------------------------
__global__ __launch_bounds__(256) void part2_kernel(const uint32_t* __restrict__ ptr,
                                                    const uint2* __restrict__ part,
                                                    uint32_t* __restrict__ cursor,
                                                    uint2* __restrict__ sorted) {
    int b = blockIdx.x & (NB - 1);
    int s = blockIdx.x >> 5;                       // 0..15
    uint32_t rbeg = ptr[(size_t)b * SEGS_PER_BUCKET];
    uint32_t rend = (b == NB - 1) ? (uint32_t)N_EDGES : ptr[(size_t)(b + 1) * SEGS_PER_BUCKET];
    uint32_t len  = rend - rbeg;
    uint32_t cbeg = rbeg + (uint32_t)(((uint64_t)len * (uint32_t)s) >> 4);
    uint32_t cend = rbeg + (uint32_t)(((uint64_t)len * (uint32_t)(s + 1)) >> 4);
    for (uint32_t i = cbeg + threadIdx.x; i < cend; i += 256) {
        uint2 r = part[i];
        uint32_t src = r.x & 0x1FFFFu;
        uint32_t dl  = (r.x >> 17) & 0xFFFu;
        uint32_t rel = r.x >> 29;
        uint32_t seg = (uint32_t)b * SEGS_PER_BUCKET + dl * 8u + rel;
        uint32_t pos = atomicAdd(&cursor[seg], 1u);
        sorted[pos] = make_uint2(src, r.y);
    }
}

// ---------------------------------------------------------------------------
// FUSED gather-aggregate + dense MFMA (round-4 verified). Lane l of wave w
// gathers its (node,rel) segment's edges, accumulates fp32 in registers,
// normalizes, packs bf16x8 A-fragment, MFMAs directly. `num` never exists.
// MFMA layouts (HW-verified): A[m=lane&15][k=quad*8+j]; B[k][n=lane&15];
// C row=quad*4+reg, col=lane&15.
// ---------------------------------------------------------------------------
__global__ __launch_bounds__(256) void fused_dense_kernel(
    const uint32_t* __restrict__ ptr,
    const uint2* __restrict__ sorted,
    const uint16_t* __restrict__ xbf,
    const uint16_t* __restrict__ sWg,
    const float* __restrict__ biasv,
    const int* __restrict__ flag,
    void* __restrict__ out)
{
    __shared__ uint16_t sB[SWG_ELEMS]; // 36KB
    int f32 = *flag;

    #pragma unroll
    for (int it = 0; it < SWG_ELEMS / (256 * 8); ++it) {   // 9 iterations
        int idx = (it * 256 + threadIdx.x) * 8;
        *(bf16x8*)(sB + idx) = *(const bf16x8*)(sWg + idx);
    }
    __syncthreads();

    int wid  = threadIdx.x >> 6;
    int lane = threadIdx.x & 63;
    int quad = lane >> 4;
    int m    = lane & 15;

    int n0 = blockIdx.x * 64 + wid * 16;
    int n  = n0 + m;
    int nc = (n < N_NODES) ? n : (N_NODES - 1);

    float bias[4];
    #pragma unroll
    for (int ot = 0; ot < 4; ++ot) bias[ot] = biasv[ot * 16 + m];

    f32x4 acc[4];
    #pragma unroll
    for (int ot = 0; ot < 4; ++ot) acc[ot] = (f32x4){0.f, 0.f, 0.f, 0.f};

    #pragma unroll
    for (int kk = 0; kk < N_KK; ++kk) {
        bf16x8 a;
        if (kk < 8) {
            // gather-aggregate this lane's segment (node nc, relation kk),
            // features [quad*8, quad*8+8)
            int seg = nc * N_REL + kk;
            int beg = (int)ptr[seg];
            int end = (int)ptr[seg + 1];
            float s0 = 0.f, s1 = 0.f, s2 = 0.f, s3 = 0.f;
            float s4 = 0.f, s5 = 0.f, s6 = 0.f, s7 = 0.f, sw = 0.f;
            for (int i = beg; i < end; ++i) {
                uint2 d = sorted[i];             // shared by the 4 quads of node nc
                float w = __uint_as_float(d.y);
                const uint4 xv = *(const uint4*)(xbf + (size_t)d.x * IN_DIM + quad * 8);
                s0 += w * bflo(xv.x); s1 += w * bfhi(xv.x);
                s2 += w * bflo(xv.y); s3 += w * bfhi(xv.y);
                s4 += w * bflo(xv.z); s5 += w * bfhi(xv.z);
                s6 += w * bflo(xv.w); s7 += w * bfhi(xv.w);
                sw += w;
            }
            float inv = 1.0f / (sw + EPS);       // empty segment -> 0
            a[0] = (short)f2bf(s0 * inv); a[1] = (short)f2bf(s1 * inv);
            a[2] = (short)f2bf(s2 * inv); a[3] = (short)f2bf(s3 * inv);
            a[4] = (short)f2bf(s4 * inv); a[5] = (short)f2bf(s5 * inv);
            a[6] = (short)f2bf(s6 * inv); a[7] = (short)f2bf(s7 * inv);
        } else {
            a = *(const bf16x8*)(xbf + (size_t)nc * IN_DIM + quad * 8);
        }
        #pragma unroll
        for (int ot = 0; ot < 4; ++ot) {
            bf16x8 b = *(const bf16x8*)(sB + ((kk * 4 + ot) * 64 + lane) * 8);
            acc[ot] = __builtin_amdgcn_mfma_f32_16x16x32_bf16(a, b, acc[ot], 0, 0, 0);
        }
    }

    #pragma unroll
    for (int ot = 0; ot < 4; ++ot) {
        #pragma unroll
        for (int reg = 0; reg < 4; ++reg) {
            int node = n0 + quad * 4 + reg;
            if (node >= N_NODES) continue;
            int o = ot * 16 + m;
            float v = fmaxf(acc[ot][reg] + bias[ot], 0.0f);
            if (f32) ((float*)out)[(size_t)node * OUT_DIM + o] = v;
            else     ((uint16_t*)out)[(size_t)node * OUT_DIM + o] = f2bf(v);
        }
    }
}

// ===========================================================================
extern "C" void kernel_launch(void* const* d_in, const int* in_sizes, int n_in,
                              void* d_out, int out_size, void* d_ws, size_t ws_size,
                              hipStream_t stream) {
    const void* x  = d_in[0];
    const int* el  = (const int*)d_in[1];
    const void* ew = d_in[2];
    const void* Wl = d_in[3];
    const void* bl = d_in[4];
    const void* Ws = d_in[5];
    const void* bs = d_in[6];

    // workspace:
    // [flag 64B][gcursor 128B][cursor 3.2MB][ptr (NSEG+1)*4][bsum 16KB]
    // [part 12.8MB][sorted 12.8MB][sWg 36KB][biasv 256B][xbf 6.4MB]  ~38.6MB
    const size_t OFF_GC   = 64;
    const size_t OFF_CUR  = OFF_GC + 128;                 // gcursor+cursor: one memset
    const size_t OFF_PTR  = OFF_CUR + (size_t)NSEG * 4;
    const size_t OFF_BS   = OFF_PTR + (((size_t)(NSEG + 1) * 4 + 63) & ~(size_t)63);
    const size_t OFF_PART = OFF_BS + 16384;
    const size_t OFF_SORT = OFF_PART + (size_t)N_EDGES * 8;
    const size_t OFF_SWG  = OFF_SORT + (size_t)N_EDGES * 8;
    const size_t OFF_BIAS = OFF_SWG + (size_t)SWG_ELEMS * 2;
    const size_t OFF_XBF  = OFF_BIAS + 256;
    const size_t REQ      = OFF_XBF + (size_t)N_NODES * IN_DIM * 2;
    if (ws_size < REQ) return;

    int*      flag    = (int*)d_ws;
    uint32_t* gcursor = (uint32_t*)((char*)d_ws + OFF_GC);
    uint32_t* cursor  = (uint32_t*)((char*)d_ws + OFF_CUR);
    uint32_t* ptr     = (uint32_t*)((char*)d_ws + OFF_PTR);
    uint32_t* bsum    = (uint32_t*)((char*)d_ws + OFF_BS);
    uint2*    part    = (uint2*)((char*)d_ws + OFF_PART);
    uint2*    sorted  = (uint2*)((char*)d_ws + OFF_SORT);
    uint16_t* sWg     = (uint16_t*)((char*)d_ws + OFF_SWG);
    float*    biasv   = (float*)((char*)d_ws + OFF_BIAS);
    uint16_t* xbf     = (uint16_t*)((char*)d_ws + OFF_XBF);

    // zero gcursor + cursor (contiguous, 3.2MB)
    (void)hipMemsetAsync((char*)d_ws + OFF_GC, 0, 128 + (size_t)NSEG * 4, stream);

    detect_kernel<<<1, 256, 0, stream>>>((const uint32_t*)x, flag);

    setup_kernel<<<HIST_BLOCKS + XBF_BLOCKS + PREP_BLOCKS, 256, 0, stream>>>(
        el, x, Wl, Ws, bl, bs, flag, cursor, xbf, sWg, biasv);

    scan1_kernel<<<SCAN_NB, 256, 0, stream>>>(cursor, bsum);
    scan3_kernel<<<SCAN_NB, 256, 0, stream>>>(bsum, ptr, cursor);

    part1_kernel<<<P1_BLOCKS, 256, 0, stream>>>(el, ew, flag, ptr, gcursor, part);
    part2_kernel<<<NB * P2_SUB, 256, 0, stream>>>(ptr, part, cursor, sorted);

    fused_dense_kernel<<<(N_NODES + 63) / 64, 256, 0, stream>>>(ptr, sorted, xbf, sWg, biasv, flag, d_out);
}

// Round 6
// 277.133 us; speedup vs baseline: 1.3429x; 1.3429x over previous
//
#include <hip/hip_runtime.h>
#include <stdint.h>

#define N_NODES 100000
#define N_EDGES 1600000
#define IN_DIM 32
#define OUT_DIM 64
#define N_REL 8
#define NSEG (N_NODES * N_REL)     // 800000
#define EPS 1e-10f
#define N_KK 9                      // K-tiles of 32 (8 rel + 1 self)
#define SWG_ELEMS (N_KK * 4 * 64 * 8)  // 18432 bf16 in b-frag order

// counting-sort scan geometry
#define SCAN_ELEMS 4096                         // elements per scan block (256 thr x 16)
#define SCAN_NB ((NSEG + SCAN_ELEMS - 1) / SCAN_ELEMS)  // 196 (<=256: in-block reduce ok)

// two-phase partition geometry
#define NB 256                                  // dst-range buckets
#define NODES_PER_BUCKET 391                    // ceil(100000/256); last bucket short
#define SEGS_PER_BUCKET (NODES_PER_BUCKET * N_REL)  // 3128
#define P1_EDGES 4096                           // edges per part1 block (16/thread)
#define P1_BLOCKS ((N_EDGES + P1_EDGES - 1) / P1_EDGES) // 391
#define P2_CAP 7168                             // LDS staging records (mean 6250 + 11 sigma)

// merged setup kernel block ranges
#define HIST_BLOCKS ((N_EDGES + 255) / 256)               // 6250
#define XBF_BLOCKS  ((N_NODES * IN_DIM / 8 + 255) / 256)  // 1563
#define PREP_BLOCKS ((SWG_ELEMS + OUT_DIM + 255) / 256)   // 73

typedef __attribute__((ext_vector_type(8))) short bf16x8;
typedef __attribute__((ext_vector_type(4))) float f32x4;

static __device__ __forceinline__ float bflo(uint32_t u) { return __uint_as_float(u << 16); }
static __device__ __forceinline__ float bfhi(uint32_t u) { return __uint_as_float(u & 0xffff0000u); }
static __device__ __forceinline__ uint16_t f2bf(float f) {
    uint32_t u = __float_as_uint(f);
    return (uint16_t)((u + 0x7fffu + ((u >> 16) & 1u)) >> 16); // RNE
}

// ---------------------------------------------------------------------------
// Dtype probe (earlier rounds proved fp32; kept for robustness, ~3us).
// ---------------------------------------------------------------------------
__global__ __launch_bounds__(256) void detect_kernel(const uint32_t* __restrict__ xw,
                                                     int* __restrict__ flag) {
    __shared__ int cnt;
    if (threadIdx.x == 0) cnt = 0;
    __syncthreads();
    int c = 0;
    for (int k = threadIdx.x; k < 4096; k += 256) {
        uint32_t w = xw[k];
        uint32_t e = (w >> 7) & 0xffu;
        c += (e >= 160u) ? 1 : 0;
    }
    atomicAdd(&cnt, c);
    __syncthreads();
    if (threadIdx.x == 0) *flag = (cnt > 64) ? 1 : 0;  // 1 = fp32 inputs
}

// ---------------------------------------------------------------------------
// setup: merged hist + xbf + prep (block-range dispatch).
// ---------------------------------------------------------------------------
__global__ __launch_bounds__(256) void setup_kernel(
    const int* __restrict__ el,
    const void* __restrict__ x,
    const void* __restrict__ Wl, const void* __restrict__ Ws,
    const void* __restrict__ bl, const void* __restrict__ bs,
    const int* __restrict__ flag,
    uint32_t* __restrict__ cnt,       // histogram region (zeroed)
    uint16_t* __restrict__ xbf,
    uint16_t* __restrict__ sWg,
    float* __restrict__ biasv)
{
    int bid = blockIdx.x;
    if (bid < HIST_BLOCKS) {
        int e = bid * 256 + threadIdx.x;
        if (e >= N_EDGES) return;
        int dst = el[e * 3 + 1];
        int rel = el[e * 3 + 2];
        atomicAdd(&cnt[dst * N_REL + rel], 1u);
        return;
    }
    bid -= HIST_BLOCKS;
    if (bid < XBF_BLOCKS) {
        int i = bid * 256 + threadIdx.x;           // one thread = 8 elements
        if (i >= N_NODES * IN_DIM / 8) return;
        if (*flag) {
            const float4 v0 = ((const float4*)x)[(size_t)i * 2];
            const float4 v1 = ((const float4*)x)[(size_t)i * 2 + 1];
            bf16x8 r;
            r[0] = (short)f2bf(v0.x); r[1] = (short)f2bf(v0.y);
            r[2] = (short)f2bf(v0.z); r[3] = (short)f2bf(v0.w);
            r[4] = (short)f2bf(v1.x); r[5] = (short)f2bf(v1.y);
            r[6] = (short)f2bf(v1.z); r[7] = (short)f2bf(v1.w);
            *(bf16x8*)(xbf + (size_t)i * 8) = r;
        } else {
            *(bf16x8*)(xbf + (size_t)i * 8) = ((const bf16x8*)x)[i];
        }
        return;
    }
    bid -= XBF_BLOCKS;
    {
        int f32 = *flag;
        int idx = bid * 256 + threadIdx.x;
        if (idx < SWG_ELEMS) {
            int j    = idx & 7;
            int lane = (idx >> 3) & 63;
            int ot   = (idx >> 9) & 3;
            int kk   = idx >> 11;
            int quad = lane >> 4;
            int k = kk * 32 + quad * 8 + j;
            int o = ot * 16 + (lane & 15);
            if (f32) {
                float v = (k < 256) ? ((const float*)Wl)[(size_t)k * OUT_DIM + o]
                                    : ((const float*)Ws)[(size_t)(k - 256) * OUT_DIM + o];
                sWg[idx] = f2bf(v);
            } else {
                sWg[idx] = (k < 256) ? ((const uint16_t*)Wl)[(size_t)k * OUT_DIM + o]
                                     : ((const uint16_t*)Ws)[(size_t)(k - 256) * OUT_DIM + o];
            }
        } else if (idx < SWG_ELEMS + OUT_DIM) {
            int o = idx - SWG_ELEMS;
            if (f32) biasv[o] = ((const float*)bl)[o] + ((const float*)bs)[o];
            else     biasv[o] = bflo((uint32_t)((const uint16_t*)bl)[o])
                              + bflo((uint32_t)((const uint16_t*)bs)[o]);
        }
    }
}

// ---------------------------------------------------------------------------
// scan1: per-block sums of counts (SCAN_ELEMS per block) -> bsum[196].
// ---------------------------------------------------------------------------
__global__ __launch_bounds__(256) void scan1_kernel(const uint32_t* __restrict__ cnt,
                                                    uint32_t* __restrict__ bsum) {
    int base = blockIdx.x * SCAN_ELEMS + threadIdx.x * 16;
    uint32_t s = 0;
    #pragma unroll
    for (int j = 0; j < 16; ++j) {
        int i = base + j;
        s += (i < NSEG) ? cnt[i] : 0u;
    }
    __shared__ uint32_t ls[256];
    ls[threadIdx.x] = s;
    __syncthreads();
    #pragma unroll
    for (int off = 128; off > 0; off >>= 1) {
        if (threadIdx.x < off) ls[threadIdx.x] += ls[threadIdx.x + off];
        __syncthreads();
    }
    if (threadIdx.x == 0) bsum[blockIdx.x] = ls[0];
}

// ---------------------------------------------------------------------------
// scan3 (scan2 folded in): block reduces bsum[0..blockIdx) in-block, then
// in-block exclusive scan of counts -> ptr.
// ---------------------------------------------------------------------------
__global__ __launch_bounds__(256) void scan3_kernel(const uint32_t* __restrict__ bsum,
                                                    const uint32_t* __restrict__ cnt,
                                                    uint32_t* __restrict__ ptr) {
    int tid = threadIdx.x;
    __shared__ uint32_t ls[256];

    // boff = sum of bsum[i] for i < blockIdx.x
    ls[tid] = (tid < (int)blockIdx.x) ? bsum[tid] : 0u;
    __syncthreads();
    #pragma unroll
    for (int off = 128; off > 0; off >>= 1) {
        if (tid < off) ls[tid] += ls[tid + off];
        __syncthreads();
    }
    uint32_t boff = ls[0];
    __syncthreads();

    int base = blockIdx.x * SCAN_ELEMS + tid * 16;
    uint32_t v[16];
    uint32_t run = 0;
    #pragma unroll
    for (int j = 0; j < 16; ++j) {
        int i = base + j;
        uint32_t c = (i < NSEG) ? cnt[i] : 0u;
        v[j] = run;
        run += c;
    }
    ls[tid] = run;
    __syncthreads();
    for (int off = 1; off < 256; off <<= 1) {
        uint32_t t = (tid >= off) ? ls[tid - off] : 0u;
        __syncthreads();
        ls[tid] += t;
        __syncthreads();
    }
    uint32_t texcl = ls[tid] - run;
    #pragma unroll
    for (int j = 0; j < 16; ++j) {
        int i = base + j;
        if (i < NSEG) ptr[i] = boff + texcl + v[j];
    }
    if (blockIdx.x == 0 && tid == 0) ptr[NSEG] = N_EDGES;
}

// ---------------------------------------------------------------------------
// part1: bucket-partition edges into 256 dst-range buckets (391 nodes each).
// Block: 4096 edges -> LDS histogram -> one global atomic per bucket reserves
// a contiguous window -> ~128B contiguous batches. el/ew read ONCE.
// Record: uint2{ src | dl<<17 | rel<<26 , w_bits } (17+9+3 = 29 bits).
// ---------------------------------------------------------------------------
__global__ __launch_bounds__(256) void part1_kernel(const int* __restrict__ el,
                                                    const void* __restrict__ ew,
                                                    const int* __restrict__ flag,
                                                    const uint32_t* __restrict__ ptr,
                                                    uint32_t* __restrict__ gcursor,
                                                    uint2* __restrict__ part) {
    __shared__ uint32_t cnt[NB], base[NB];
    int tid = threadIdx.x;
    cnt[tid] = 0;                                  // NB == 256 == blockDim
    __syncthreads();
    int f32 = *flag;
    int e0 = blockIdx.x * P1_EDGES;

    uint32_t meta[16], wbits[16], bk[16], my[16];
    #pragma unroll
    for (int j = 0; j < 16; ++j) {
        int e = e0 + j * 256 + tid;
        if (e < N_EDGES) {
            int src = el[e * 3 + 0];
            int dst = el[e * 3 + 1];
            int rel = el[e * 3 + 2];
            int b  = dst / NODES_PER_BUCKET;           // 0..255 (magic-mul)
            int dl = dst - b * NODES_PER_BUCKET;       // < 391 (9 bits)
            meta[j]  = (uint32_t)src | ((uint32_t)dl << 17) | ((uint32_t)rel << 26);
            wbits[j] = f32 ? ((const uint32_t*)ew)[e]
                           : ((uint32_t)((const uint16_t*)ew)[e] << 16);
            bk[j] = (uint32_t)b;
            my[j] = atomicAdd(&cnt[b], 1u);
        } else {
            bk[j] = 0xffffffffu;
        }
    }
    __syncthreads();
    {
        uint32_t c = cnt[tid];
        base[tid] = c ? (ptr[(size_t)tid * SEGS_PER_BUCKET] + atomicAdd(&gcursor[tid], c)) : 0u;
    }
    __syncthreads();
    #pragma unroll
    for (int j = 0; j < 16; ++j) {
        if (bk[j] != 0xffffffffu)
            part[(size_t)base[bk[j]] + my[j]] = make_uint2(meta[j], wbits[j]);
    }
}

// ---------------------------------------------------------------------------
// part2: per-bucket segment-sort ENTIRELY IN LDS, then coalesced stream-out.
// Round-5 lesson (measured): scattered 8B global stores do NOT write-combine
// in L2 (93MB HBM writes for 12.8MB payload, even with XCD-pinned 400KB
// windows). So: scatter into LDS staging (LDS atomics, no global randomness),
// then write sorted[rbeg..rend) linearly -> full-line writes by construction.
// One block per bucket; bucket segs are globally contiguous (seg=node*8+rel,
// nodes contiguous). Overflow (>P2_CAP, mean+11sigma) degrades gracefully to
// direct scatter for the tail records only.
// ---------------------------------------------------------------------------
__global__ __launch_bounds__(256) void part2_kernel(const uint32_t* __restrict__ ptr,
                                                    const uint2* __restrict__ part,
                                                    uint2* __restrict__ sorted) {
    __shared__ uint32_t lcur[SEGS_PER_BUCKET];   // 12.5KB local cursors
    __shared__ uint2 stage[P2_CAP];              // 56KB staging
    int b = blockIdx.x;
    int segbase = b * SEGS_PER_BUCKET;
    int nloc = NSEG - segbase;
    if (nloc > SEGS_PER_BUCKET) nloc = SEGS_PER_BUCKET;
    uint32_t rbeg = ptr[segbase];
    uint32_t rend = ptr[segbase + nloc];
    for (int s = threadIdx.x; s < nloc; s += 256)
        lcur[s] = ptr[segbase + s] - rbeg;       // relative exclusive offsets
    __syncthreads();
    for (uint32_t i = rbeg + threadIdx.x; i < rend; i += 256) {
        uint2 r = part[i];                       // contiguous read
        uint32_t src = r.x & 0x1FFFFu;
        uint32_t dl  = (r.x >> 17) & 0x1FFu;
        uint32_t rel = r.x >> 26;
        uint32_t pos = atomicAdd(&lcur[dl * 8u + rel], 1u);
        if (pos < P2_CAP) stage[pos] = make_uint2(src, r.y);
        else              sorted[(size_t)rbeg + pos] = make_uint2(src, r.y); // rare overflow
    }
    __syncthreads();
    uint32_t len = rend - rbeg;
    if (len > P2_CAP) len = P2_CAP;
    for (uint32_t i = threadIdx.x; i < len; i += 256)
        sorted[(size_t)rbeg + i] = stage[i];     // coalesced stream-out
}

// ---------------------------------------------------------------------------
// FUSED gather-aggregate + dense MFMA (round-4 verified). Lane l of wave w
// gathers its (node,rel) segment's edges, accumulates fp32 in registers,
// normalizes, packs bf16x8 A-fragment, MFMAs directly.
// MFMA layouts (HW-verified): A[m=lane&15][k=quad*8+j]; B[k][n=lane&15];
// C row=quad*4+reg, col=lane&15.
// ---------------------------------------------------------------------------
__global__ __launch_bounds__(256) void fused_dense_kernel(
    const uint32_t* __restrict__ ptr,
    const uint2* __restrict__ sorted,
    const uint16_t* __restrict__ xbf,
    const uint16_t* __restrict__ sWg,
    const float* __restrict__ biasv,
    const int* __restrict__ flag,
    void* __restrict__ out)
{
    __shared__ uint16_t sB[SWG_ELEMS]; // 36KB
    int f32 = *flag;

    #pragma unroll
    for (int it = 0; it < SWG_ELEMS / (256 * 8); ++it) {   // 9 iterations
        int idx = (it * 256 + threadIdx.x) * 8;
        *(bf16x8*)(sB + idx) = *(const bf16x8*)(sWg + idx);
    }
    __syncthreads();

    int wid  = threadIdx.x >> 6;
    int lane = threadIdx.x & 63;
    int quad = lane >> 4;
    int m    = lane & 15;

    int n0 = blockIdx.x * 64 + wid * 16;
    int n  = n0 + m;
    int nc = (n < N_NODES) ? n : (N_NODES - 1);

    float bias[4];
    #pragma unroll
    for (int ot = 0; ot < 4; ++ot) bias[ot] = biasv[ot * 16 + m];

    f32x4 acc[4];
    #pragma unroll
    for (int ot = 0; ot < 4; ++ot) acc[ot] = (f32x4){0.f, 0.f, 0.f, 0.f};

    #pragma unroll
    for (int kk = 0; kk < N_KK; ++kk) {
        bf16x8 a;
        if (kk < 8) {
            int seg = nc * N_REL + kk;
            int beg = (int)ptr[seg];
            int end = (int)ptr[seg + 1];
            float s0 = 0.f, s1 = 0.f, s2 = 0.f, s3 = 0.f;
            float s4 = 0.f, s5 = 0.f, s6 = 0.f, s7 = 0.f, sw = 0.f;
            for (int i = beg; i < end; ++i) {
                uint2 d = sorted[i];             // shared by the 4 quads of node nc
                float w = __uint_as_float(d.y);
                const uint4 xv = *(const uint4*)(xbf + (size_t)d.x * IN_DIM + quad * 8);
                s0 += w * bflo(xv.x); s1 += w * bfhi(xv.x);
                s2 += w * bflo(xv.y); s3 += w * bfhi(xv.y);
                s4 += w * bflo(xv.z); s5 += w * bfhi(xv.z);
                s6 += w * bflo(xv.w); s7 += w * bfhi(xv.w);
                sw += w;
            }
            float inv = 1.0f / (sw + EPS);       // empty segment -> 0
            a[0] = (short)f2bf(s0 * inv); a[1] = (short)f2bf(s1 * inv);
            a[2] = (short)f2bf(s2 * inv); a[3] = (short)f2bf(s3 * inv);
            a[4] = (short)f2bf(s4 * inv); a[5] = (short)f2bf(s5 * inv);
            a[6] = (short)f2bf(s6 * inv); a[7] = (short)f2bf(s7 * inv);
        } else {
            a = *(const bf16x8*)(xbf + (size_t)nc * IN_DIM + quad * 8);
        }
        #pragma unroll
        for (int ot = 0; ot < 4; ++ot) {
            bf16x8 b = *(const bf16x8*)(sB + ((kk * 4 + ot) * 64 + lane) * 8);
            acc[ot] = __builtin_amdgcn_mfma_f32_16x16x32_bf16(a, b, acc[ot], 0, 0, 0);
        }
    }

    #pragma unroll
    for (int ot = 0; ot < 4; ++ot) {
        #pragma unroll
        for (int reg = 0; reg < 4; ++reg) {
            int node = n0 + quad * 4 + reg;
            if (node >= N_NODES) continue;
            int o = ot * 16 + m;
            float v = fmaxf(acc[ot][reg] + bias[ot], 0.0f);
            if (f32) ((float*)out)[(size_t)node * OUT_DIM + o] = v;
            else     ((uint16_t*)out)[(size_t)node * OUT_DIM + o] = f2bf(v);
        }
    }
}

// ===========================================================================
extern "C" void kernel_launch(void* const* d_in, const int* in_sizes, int n_in,
                              void* d_out, int out_size, void* d_ws, size_t ws_size,
                              hipStream_t stream) {
    const void* x  = d_in[0];
    const int* el  = (const int*)d_in[1];
    const void* ew = d_in[2];
    const void* Wl = d_in[3];
    const void* bl = d_in[4];
    const void* Ws = d_in[5];
    const void* bs = d_in[6];

    // workspace:
    // [flag 64B][gcursor 1KB][cnt 3.2MB][ptr (NSEG+1)*4][bsum 16KB]
    // [part 12.8MB][sorted 12.8MB][sWg 36KB][biasv 256B][xbf 6.4MB]  ~38.5MB
    const size_t OFF_GC   = 64;
    const size_t OFF_CNT  = OFF_GC + NB * 4;              // gcursor+cnt: one memset
    const size_t OFF_PTR  = OFF_CNT + (size_t)NSEG * 4;
    const size_t OFF_BS   = OFF_PTR + (((size_t)(NSEG + 1) * 4 + 63) & ~(size_t)63);
    const size_t OFF_PART = OFF_BS + 16384;
    const size_t OFF_SORT = OFF_PART + (size_t)N_EDGES * 8;
    const size_t OFF_SWG  = OFF_SORT + (size_t)N_EDGES * 8;
    const size_t OFF_BIAS = OFF_SWG + (size_t)SWG_ELEMS * 2;
    const size_t OFF_XBF  = OFF_BIAS + 256;
    const size_t REQ      = OFF_XBF + (size_t)N_NODES * IN_DIM * 2;
    if (ws_size < REQ) return;

    int*      flag    = (int*)d_ws;
    uint32_t* gcursor = (uint32_t*)((char*)d_ws + OFF_GC);
    uint32_t* cnt     = (uint32_t*)((char*)d_ws + OFF_CNT);
    uint32_t* ptr     = (uint32_t*)((char*)d_ws + OFF_PTR);
    uint32_t* bsum    = (uint32_t*)((char*)d_ws + OFF_BS);
    uint2*    part    = (uint2*)((char*)d_ws + OFF_PART);
    uint2*    sorted  = (uint2*)((char*)d_ws + OFF_SORT);
    uint16_t* sWg     = (uint16_t*)((char*)d_ws + OFF_SWG);
    float*    biasv   = (float*)((char*)d_ws + OFF_BIAS);
    uint16_t* xbf     = (uint16_t*)((char*)d_ws + OFF_XBF);

    // zero gcursor + cnt (contiguous, ~3.2MB)
    (void)hipMemsetAsync((char*)d_ws + OFF_GC, 0, NB * 4 + (size_t)NSEG * 4, stream);

    detect_kernel<<<1, 256, 0, stream>>>((const uint32_t*)x, flag);

    setup_kernel<<<HIST_BLOCKS + XBF_BLOCKS + PREP_BLOCKS, 256, 0, stream>>>(
        el, x, Wl, Ws, bl, bs, flag, cnt, xbf, sWg, biasv);

    scan1_kernel<<<SCAN_NB, 256, 0, stream>>>(cnt, bsum);
    scan3_kernel<<<SCAN_NB, 256, 0, stream>>>(bsum, cnt, ptr);

    part1_kernel<<<P1_BLOCKS, 256, 0, stream>>>(el, ew, flag, ptr, gcursor, part);
    part2_kernel<<<NB, 256, 0, stream>>>(ptr, part, sorted);

    fused_dense_kernel<<<(N_NODES + 63) / 64, 256, 0, stream>>>(ptr, sorted, xbf, sWg, biasv, flag, d_out);
}